// Round 5
// baseline (422.218 us; speedup 1.0000x reference)
//
#include <hip/hip_runtime.h>

typedef short v8s __attribute__((ext_vector_type(8)));
typedef float v4f __attribute__((ext_vector_type(4)));
using u16 = unsigned short;

__device__ __forceinline__ u16 f2b(float f) {
  union { float f; unsigned u; } v; v.f = f;
  unsigned r = v.u + 0x7FFFu + ((v.u >> 16) & 1u);
  return (u16)(r >> 16);
}

// ---------------- LayerNorm + bf16 casts ----------------
__global__ void ln_prep(const float* __restrict__ x, const float* __restrict__ ctx,
                        const float* __restrict__ gamma, const float* __restrict__ beta,
                        float* __restrict__ xn_f, u16* __restrict__ xn_b,
                        u16* __restrict__ ctx_b)
{
  const int tid = threadIdx.x;
  if (blockIdx.y == 0) {
    const int wid = tid >> 6, lane = tid & 63;
    const int row = blockIdx.x * 4 + wid;
    const float4 xv = *(const float4*)(x + (size_t)row * 256 + lane * 4);
    float s1 = xv.x + xv.y + xv.z + xv.w;
    float s2 = xv.x*xv.x + xv.y*xv.y + xv.z*xv.z + xv.w*xv.w;
#pragma unroll
    for (int m = 32; m >= 1; m >>= 1) {
      s1 += __shfl_xor(s1, m);
      s2 += __shfl_xor(s2, m);
    }
    const float mu  = s1 * (1.0f/256.0f);
    const float var = s2 * (1.0f/256.0f) - mu*mu;
    const float rs  = rsqrtf(var + 1e-3f);
    const float4 g = *(const float4*)(gamma + lane*4);
    const float4 b = *(const float4*)(beta  + lane*4);
    float4 y;
    y.x = (xv.x-mu)*rs*g.x + b.x;
    y.y = (xv.y-mu)*rs*g.y + b.y;
    y.z = (xv.z-mu)*rs*g.z + b.z;
    y.w = (xv.w-mu)*rs*g.w + b.w;
    *(float4*)(xn_f + (size_t)row*256 + lane*4) = y;
    ushort4 yb; yb.x=f2b(y.x); yb.y=f2b(y.y); yb.z=f2b(y.z); yb.w=f2b(y.w);
    *(ushort4*)(xn_b + (size_t)row*256 + lane*4) = yb;
  } else {
    const size_t idx = (size_t)blockIdx.x * 1024 + (size_t)tid * 4;
    const float4 cv = *(const float4*)(ctx + idx);
    ushort4 cb; cb.x=f2b(cv.x); cb.y=f2b(cv.y); cb.z=f2b(cv.z); cb.w=f2b(cv.w);
    *(ushort4*)(ctx_b + idx) = cb;
  }
}

// ---------------- weight transpose + bf16 cast (LDS-tiled) ----------------
__global__ void wtrans(const float* __restrict__ wq, const float* __restrict__ wk,
                       const float* __restrict__ wv, const float* __restrict__ wp,
                       u16* __restrict__ tq, u16* __restrict__ tk,
                       u16* __restrict__ tv, u16* __restrict__ tp)
{
  const float* src; u16* dst;
  switch (blockIdx.y) {
    case 0:  src = wq; dst = tq; break;
    case 1:  src = wk; dst = tk; break;
    case 2:  src = wv; dst = tv; break;
    default: src = wp; dst = tp; break;
  }
  __shared__ float tile[64][65];
  const int t = threadIdx.x;
  const int r0 = (blockIdx.x & 3) * 64, c0 = (blockIdx.x >> 2) * 64;
  const int c = t & 63, r = t >> 6;
#pragma unroll
  for (int j = 0; j < 16; j++)
    tile[r + j*4][c] = src[(size_t)(r0 + r + j*4) * 256 + c0 + c];
  __syncthreads();
#pragma unroll
  for (int j = 0; j < 16; j++)
    dst[(size_t)(c0 + r + j*4) * 256 + r0 + c] = f2b(tile[c][r + j*4]);
}

// ---------------- q/k/v GEMM ----------------
__global__ __launch_bounds__(256) void gemm_qkv(
    const u16* __restrict__ xn_b, const u16* __restrict__ ctx_b,
    const u16* __restrict__ wqt, const u16* __restrict__ wkt, const u16* __restrict__ wvt,
    const float* __restrict__ bq, const float* __restrict__ bk, const float* __restrict__ bv,
    u16* __restrict__ qo, u16* __restrict__ ko, u16* __restrict__ vto)
{
  const int mode = blockIdx.y;
  const u16* A; const u16* Wt; const float* bias;
  if (mode == 0)      { A = xn_b;  Wt = wqt; bias = bq; }
  else if (mode == 1) { A = ctx_b; Wt = wkt; bias = bk; }
  else                { A = ctx_b; Wt = wvt; bias = bv; }
  const int wid = threadIdx.x >> 6, lane = threadIdx.x & 63;
  const int lm = lane & 15, q4 = lane >> 4;
  const int m0 = blockIdx.x * 64 + wid * 16;
  const u16* arow = A + (size_t)(m0 + lm) * 256 + q4 * 8;
  v8s af[8];
#pragma unroll
  for (int kf = 0; kf < 8; kf++) af[kf] = *(const v8s*)(arow + kf * 32);
#pragma unroll
  for (int ct = 0; ct < 16; ct++) {
    const int c = ct * 16 + lm;
    const u16* wrow = Wt + (size_t)c * 256 + q4 * 8;
    v4f acc = {0.f, 0.f, 0.f, 0.f};
#pragma unroll
    for (int kf = 0; kf < 8; kf++)
      acc = __builtin_amdgcn_mfma_f32_16x16x32_bf16(af[kf], *(const v8s*)(wrow + kf * 32), acc, 0, 0, 0);
    const float bb = bias[c];
    if (mode == 2) {
      const int b = m0 >> 12;
      const int s = (m0 & 4095) + q4 * 4;
      ushort4 pk;
      pk.x = f2b(acc[0] + bb); pk.y = f2b(acc[1] + bb);
      pk.z = f2b(acc[2] + bb); pk.w = f2b(acc[3] + bb);
      *(ushort4*)(vto + (size_t)b * 1048576 + (size_t)c * 4096 + s) = pk;
    } else {
      u16* out = (mode == 0) ? qo : ko;
#pragma unroll
      for (int r = 0; r < 4; r++)
        out[(size_t)(m0 + q4 * 4 + r) * 256 + c] = f2b(acc[r] + bb);
    }
  }
}

// ---------------- flash-style attention, v5 ----------------
// Round-3 structure (proven 184 VGPR / 19.5 KB LDS), but grid (64,4,2):
// blockIdx.z picks a 2048-key half. 512 blocks -> 2 blocks/CU -> 2 waves/SIMD,
// so one wave's MFMA covers the other's L2/barrier stalls. Blocks write
// UNNORMALIZED fp32 partial O + partial l; attn_combine sums halves.
// (No online max -> partials combine by plain addition.)
__global__ __launch_bounds__(256, 2) void attn_kernel(
    const u16* __restrict__ q, const u16* __restrict__ k,
    const u16* __restrict__ vt, float* __restrict__ Op, float* __restrict__ Lb)
{
  __shared__ u16 P[2][64][72];   // [buf][q][key] bf16, 18.4 KB
  __shared__ float Lp[4][64];
  __shared__ float Lt[64];
  const int b   = blockIdx.y;
  const int kz  = blockIdx.z;
  const int tid = threadIdx.x;
  const int w   = tid >> 6, lane = tid & 63;
  const int lm  = lane & 15, q4 = lane >> 4;
  const int m0  = blockIdx.x * 64;
  const int base = kz * 2048;
  const u16* qb = q  + (size_t)b * 4096 * 256;
  const u16* kb = k  + (size_t)b * 4096 * 256;
  const u16* vb = vt + (size_t)b * 256 * 4096;

  // Q fragments for 4 q-tiles (held all kernel)
  v8s qf[4][8];
#pragma unroll
  for (int qt = 0; qt < 4; qt++) {
    const u16* qrow = qb + (size_t)(m0 + qt * 16 + lm) * 256 + q4 * 8;
#pragma unroll
    for (int kf = 0; kf < 8; kf++) qf[qt][kf] = *(const v8s*)(qrow + kf * 32);
  }

  v4f o[4][4];
#pragma unroll
  for (int qt = 0; qt < 4; qt++)
#pragma unroll
    for (int ct = 0; ct < 4; ct++) o[qt][ct] = (v4f){0.f, 0.f, 0.f, 0.f};
  float lsum[4][4];
#pragma unroll
  for (int qt = 0; qt < 4; qt++)
#pragma unroll
    for (int r = 0; r < 4; r++) lsum[qt][r] = 0.f;

  // K fragments for first chunk of this half
  v8s kfr[8], kfr2[8];
  {
    const u16* krow = kb + (size_t)(base + w * 16 + lm) * 256 + q4 * 8;
#pragma unroll
    for (int kf = 0; kf < 8; kf++) kfr[kf] = *(const v8s*)(krow + kf * 32);
  }

  for (int s0 = base; s0 < base + 2048; s0 += 64) {
    const int pb = (s0 >> 6) & 1;
    // V loads for this chunk, issued early
    v8s vfr[4][2];
#pragma unroll
    for (int ct = 0; ct < 4; ct++) {
      const u16* vrow = vb + (size_t)(w * 64 + ct * 16 + lm) * 4096 + s0 + q4 * 8;
#pragma unroll
      for (int ks = 0; ks < 2; ks++) vfr[ct][ks] = *(const v8s*)(vrow + ks * 32);
    }
    // phase A: S[64q x 16k] strips
    v4f sc[4];
#pragma unroll
    for (int qt = 0; qt < 4; qt++) sc[qt] = (v4f){0.f, 0.f, 0.f, 0.f};
#pragma unroll
    for (int kf = 0; kf < 8; kf++)
#pragma unroll
      for (int qt = 0; qt < 4; qt++)
        sc[qt] = __builtin_amdgcn_mfma_f32_16x16x32_bf16(qf[qt][kf], kfr[kf], sc[qt], 0, 0, 0);
    // K prefetch for next chunk (wraps within the half; last-iter wrap harmless)
    {
      const int sn = base + (((s0 - base) + 64) & 2047);
      const u16* krn = kb + (size_t)(sn + w * 16 + lm) * 256 + q4 * 8;
#pragma unroll
      for (int kf = 0; kf < 8; kf++) kfr2[kf] = *(const v8s*)(krn + kf * 32);
    }
    // exp -> P
#pragma unroll
    for (int qt = 0; qt < 4; qt++)
#pragma unroll
      for (int r = 0; r < 4; r++) {
        const float e = __expf(sc[qt][r] * 0.0625f);
        lsum[qt][r] += e;
        P[pb][qt * 16 + q4 * 4 + r][w * 16 + lm] = f2b(e);
      }
    __syncthreads();
    // phase B: O[64q x 64ch(w)] += P * V
#pragma unroll
    for (int qt = 0; qt < 4; qt++) {
      const v8s pf0 = *(const v8s*)(&P[pb][qt * 16 + lm][q4 * 8]);
      const v8s pf1 = *(const v8s*)(&P[pb][qt * 16 + lm][32 + q4 * 8]);
#pragma unroll
      for (int ct = 0; ct < 4; ct++) {
        o[qt][ct] = __builtin_amdgcn_mfma_f32_16x16x32_bf16(pf0, vfr[ct][0], o[qt][ct], 0, 0, 0);
        o[qt][ct] = __builtin_amdgcn_mfma_f32_16x16x32_bf16(pf1, vfr[ct][1], o[qt][ct], 0, 0, 0);
      }
    }
#pragma unroll
    for (int kf = 0; kf < 8; kf++) kfr[kf] = kfr2[kf];
  }

  // partial l: butterfly over the 16 key-lanes, then sum the 4 waves
#pragma unroll
  for (int qt = 0; qt < 4; qt++)
#pragma unroll
    for (int r = 0; r < 4; r++) {
      float t = lsum[qt][r];
      t += __shfl_xor(t, 1); t += __shfl_xor(t, 2);
      t += __shfl_xor(t, 4); t += __shfl_xor(t, 8);
      lsum[qt][r] = t;
    }
  if (lm == 0) {
#pragma unroll
    for (int qt = 0; qt < 4; qt++)
#pragma unroll
      for (int r = 0; r < 4; r++) Lp[w][qt * 16 + q4 * 4 + r] = lsum[qt][r];
  }
  __syncthreads();
  const size_t row16k = (size_t)b * 4096 + m0;        // global row of this tile
  if (tid < 64)
    Lb[(size_t)kz * 16384 + row16k + tid] = Lp[0][tid] + Lp[1][tid] + Lp[2][tid] + Lp[3][tid];

  // unnormalized fp32 partial O
  float* opb = Op + ((size_t)kz * 16384 + row16k) * 256;
#pragma unroll
  for (int qt = 0; qt < 4; qt++)
#pragma unroll
    for (int r = 0; r < 4; r++) {
      const size_t rbase = (size_t)(qt * 16 + q4 * 4 + r) * 256 + w * 64;
#pragma unroll
      for (int ct = 0; ct < 4; ct++)
        opb[rbase + ct * 16 + lm] = o[qt][ct][r];
    }
}

// ---------------- combine the two key-half partials ----------------
// grid 4096, block 256: 4 rows/block, one row per wave, float4 per lane.
__global__ void attn_combine(const float* __restrict__ Op, const float* __restrict__ Lb,
                             u16* __restrict__ ao)
{
  const int wid = threadIdx.x >> 6, lane = threadIdx.x & 63;
  const size_t row = (size_t)blockIdx.x * 4 + wid;
  const float linv = 1.0f / (Lb[row] + Lb[16384 + row]);
  const float4 o0 = *(const float4*)(Op + row * 256 + lane * 4);
  const float4 o1 = *(const float4*)(Op + (16384 + row) * 256 + lane * 4);
  ushort4 rb;
  rb.x = f2b((o0.x + o1.x) * linv);
  rb.y = f2b((o0.y + o1.y) * linv);
  rb.z = f2b((o0.z + o1.z) * linv);
  rb.w = f2b((o0.w + o1.w) * linv);
  *(ushort4*)(ao + row * 256 + lane * 4) = rb;
}

// ---------------- proj GEMM + bias + residual ----------------
__global__ __launch_bounds__(256) void gemm_proj(
    const u16* __restrict__ A, const u16* __restrict__ Wt, const float* __restrict__ bias,
    const float* __restrict__ xn_f, float* __restrict__ out)
{
  const int wid = threadIdx.x >> 6, lane = threadIdx.x & 63;
  const int lm = lane & 15, q4 = lane >> 4;
  const int m0 = blockIdx.x * 64 + wid * 16;
  const u16* arow = A + (size_t)(m0 + lm) * 256 + q4 * 8;
  v8s af[8];
#pragma unroll
  for (int kf = 0; kf < 8; kf++) af[kf] = *(const v8s*)(arow + kf * 32);
#pragma unroll
  for (int ct = 0; ct < 16; ct++) {
    const int c = ct * 16 + lm;
    const u16* wrow = Wt + (size_t)c * 256 + q4 * 8;
    v4f acc = {0.f, 0.f, 0.f, 0.f};
#pragma unroll
    for (int kf = 0; kf < 8; kf++)
      acc = __builtin_amdgcn_mfma_f32_16x16x32_bf16(af[kf], *(const v8s*)(wrow + kf * 32), acc, 0, 0, 0);
    const float bb = bias[c];
#pragma unroll
    for (int r = 0; r < 4; r++) {
      const size_t idx = (size_t)(m0 + q4 * 4 + r) * 256 + c;
      out[idx] = xn_f[idx] + acc[r] + bb;
    }
  }
}

extern "C" void kernel_launch(void* const* d_in, const int* in_sizes, int n_in,
                              void* d_out, int out_size, void* d_ws, size_t ws_size,
                              hipStream_t stream)
{
  (void)in_sizes; (void)n_in; (void)out_size; (void)ws_size;
  const float* inputs  = (const float*)d_in[0];
  const float* context = (const float*)d_in[1];
  const float* Wq = (const float*)d_in[2];
  const float* bq = (const float*)d_in[3];
  const float* Wk = (const float*)d_in[4];
  const float* bk = (const float*)d_in[5];
  const float* Wv = (const float*)d_in[6];
  const float* bv = (const float*)d_in[7];
  const float* Wp = (const float*)d_in[8];
  const float* bp = (const float*)d_in[9];
  const float* gamma = (const float*)d_in[10];
  const float* beta  = (const float*)d_in[11];
  float* out = (float*)d_out;

  char* p = (char*)d_ws;
  float* xn_f = (float*)p; p += (size_t)16384 * 256 * 4;
  u16* xn_b   = (u16*)p;   p += (size_t)16384 * 256 * 2;
  u16* ctx_b  = (u16*)p;   p += (size_t)16384 * 256 * 2;
  u16* qbuf   = (u16*)p;   p += (size_t)16384 * 256 * 2;
  u16* kbuf   = (u16*)p;   p += (size_t)16384 * 256 * 2;
  u16* vtbuf  = (u16*)p;   p += (size_t)16384 * 256 * 2;
  u16* wqt = (u16*)p; p += (size_t)256 * 256 * 2;
  u16* wkt = (u16*)p; p += (size_t)256 * 256 * 2;
  u16* wvt = (u16*)p; p += (size_t)256 * 256 * 2;
  u16* wpt = (u16*)p; p += (size_t)256 * 256 * 2;
  float* Opart = (float*)p; p += (size_t)2 * 16384 * 256 * 4;   // 32 MB
  float* Lpart = (float*)p; p += (size_t)2 * 16384 * 4;         // 128 KB
  u16* aobuf = xn_b;  // xn_b dead after gemm_qkv

  ln_prep<<<dim3(4096, 2), 256, 0, stream>>>(inputs, context, gamma, beta, xn_f, xn_b, ctx_b);
  wtrans<<<dim3(16, 4), 256, 0, stream>>>(Wq, Wk, Wv, Wp, wqt, wkt, wvt, wpt);
  gemm_qkv<<<dim3(256, 3), 256, 0, stream>>>(xn_b, ctx_b, wqt, wkt, wvt, bq, bk, bv, qbuf, kbuf, vtbuf);
  attn_kernel<<<dim3(64, 4, 2), 256, 0, stream>>>(qbuf, kbuf, vtbuf, Opart, Lpart);
  attn_combine<<<dim3(4096), 256, 0, stream>>>(Opart, Lpart, aobuf);
  gemm_proj<<<dim3(256), 256, 0, stream>>>(aobuf, wpt, bp, xn_f, out);
}

// Round 6
// 329.262 us; speedup vs baseline: 1.2823x; 1.2823x over previous
//
#include <hip/hip_runtime.h>

typedef short v8s __attribute__((ext_vector_type(8)));
typedef float v4f __attribute__((ext_vector_type(4)));
using u16 = unsigned short;

__device__ __forceinline__ u16 f2b(float f) {
  union { float f; unsigned u; } v; v.f = f;
  unsigned r = v.u + 0x7FFFu + ((v.u >> 16) & 1u);
  return (u16)(r >> 16);
}

// ---------------- LayerNorm + bf16 casts ----------------
__global__ void ln_prep(const float* __restrict__ x, const float* __restrict__ ctx,
                        const float* __restrict__ gamma, const float* __restrict__ beta,
                        float* __restrict__ xn_f, u16* __restrict__ xn_b,
                        u16* __restrict__ ctx_b)
{
  const int tid = threadIdx.x;
  if (blockIdx.y == 0) {
    const int wid = tid >> 6, lane = tid & 63;
    const int row = blockIdx.x * 4 + wid;
    const float4 xv = *(const float4*)(x + (size_t)row * 256 + lane * 4);
    float s1 = xv.x + xv.y + xv.z + xv.w;
    float s2 = xv.x*xv.x + xv.y*xv.y + xv.z*xv.z + xv.w*xv.w;
#pragma unroll
    for (int m = 32; m >= 1; m >>= 1) {
      s1 += __shfl_xor(s1, m);
      s2 += __shfl_xor(s2, m);
    }
    const float mu  = s1 * (1.0f/256.0f);
    const float var = s2 * (1.0f/256.0f) - mu*mu;
    const float rs  = rsqrtf(var + 1e-3f);
    const float4 g = *(const float4*)(gamma + lane*4);
    const float4 b = *(const float4*)(beta  + lane*4);
    float4 y;
    y.x = (xv.x-mu)*rs*g.x + b.x;
    y.y = (xv.y-mu)*rs*g.y + b.y;
    y.z = (xv.z-mu)*rs*g.z + b.z;
    y.w = (xv.w-mu)*rs*g.w + b.w;
    *(float4*)(xn_f + (size_t)row*256 + lane*4) = y;
    ushort4 yb; yb.x=f2b(y.x); yb.y=f2b(y.y); yb.z=f2b(y.z); yb.w=f2b(y.w);
    *(ushort4*)(xn_b + (size_t)row*256 + lane*4) = yb;
  } else {
    const size_t idx = (size_t)blockIdx.x * 1024 + (size_t)tid * 4;
    const float4 cv = *(const float4*)(ctx + idx);
    ushort4 cb; cb.x=f2b(cv.x); cb.y=f2b(cv.y); cb.z=f2b(cv.z); cb.w=f2b(cv.w);
    *(ushort4*)(ctx_b + idx) = cb;
  }
}

// ---------------- weight transpose + bf16 cast (LDS-tiled) ----------------
__global__ void wtrans(const float* __restrict__ wq, const float* __restrict__ wk,
                       const float* __restrict__ wv, const float* __restrict__ wp,
                       u16* __restrict__ tq, u16* __restrict__ tk,
                       u16* __restrict__ tv, u16* __restrict__ tp)
{
  const float* src; u16* dst;
  switch (blockIdx.y) {
    case 0:  src = wq; dst = tq; break;
    case 1:  src = wk; dst = tk; break;
    case 2:  src = wv; dst = tv; break;
    default: src = wp; dst = tp; break;
  }
  __shared__ float tile[64][65];
  const int t = threadIdx.x;
  const int r0 = (blockIdx.x & 3) * 64, c0 = (blockIdx.x >> 2) * 64;
  const int c = t & 63, r = t >> 6;
#pragma unroll
  for (int j = 0; j < 16; j++)
    tile[r + j*4][c] = src[(size_t)(r0 + r + j*4) * 256 + c0 + c];
  __syncthreads();
#pragma unroll
  for (int j = 0; j < 16; j++)
    dst[(size_t)(c0 + r + j*4) * 256 + r0 + c] = f2b(tile[c][r + j*4]);
}

// ---------------- q/k/v GEMM ----------------
__global__ __launch_bounds__(256) void gemm_qkv(
    const u16* __restrict__ xn_b, const u16* __restrict__ ctx_b,
    const u16* __restrict__ wqt, const u16* __restrict__ wkt, const u16* __restrict__ wvt,
    const float* __restrict__ bq, const float* __restrict__ bk, const float* __restrict__ bv,
    u16* __restrict__ qo, u16* __restrict__ ko, u16* __restrict__ vto)
{
  const int mode = blockIdx.y;
  const u16* A; const u16* Wt; const float* bias;
  if (mode == 0)      { A = xn_b;  Wt = wqt; bias = bq; }
  else if (mode == 1) { A = ctx_b; Wt = wkt; bias = bk; }
  else                { A = ctx_b; Wt = wvt; bias = bv; }
  const int wid = threadIdx.x >> 6, lane = threadIdx.x & 63;
  const int lm = lane & 15, q4 = lane >> 4;
  const int m0 = blockIdx.x * 64 + wid * 16;
  const u16* arow = A + (size_t)(m0 + lm) * 256 + q4 * 8;
  v8s af[8];
#pragma unroll
  for (int kf = 0; kf < 8; kf++) af[kf] = *(const v8s*)(arow + kf * 32);
#pragma unroll
  for (int ct = 0; ct < 16; ct++) {
    const int c = ct * 16 + lm;
    const u16* wrow = Wt + (size_t)c * 256 + q4 * 8;
    v4f acc = {0.f, 0.f, 0.f, 0.f};
#pragma unroll
    for (int kf = 0; kf < 8; kf++)
      acc = __builtin_amdgcn_mfma_f32_16x16x32_bf16(af[kf], *(const v8s*)(wrow + kf * 32), acc, 0, 0, 0);
    const float bb = bias[c];
    if (mode == 2) {
      const int b = m0 >> 12;
      const int s = (m0 & 4095) + q4 * 4;
      ushort4 pk;
      pk.x = f2b(acc[0] + bb); pk.y = f2b(acc[1] + bb);
      pk.z = f2b(acc[2] + bb); pk.w = f2b(acc[3] + bb);
      *(ushort4*)(vto + (size_t)b * 1048576 + (size_t)c * 4096 + s) = pk;
    } else {
      u16* out = (mode == 0) ? qo : ko;
#pragma unroll
      for (int r = 0; r < 4; r++)
        out[(size_t)(m0 + q4 * 4 + r) * 256 + c] = f2b(acc[r] + bb);
    }
  }
}

// ---------------- flash-style attention, v6 ----------------
// Round-3 body verbatim (compiled to 184 VGPR there — NO min-waves launch
// bound: 184 <= 256 already hardware-allows 2 waves/SIMD; runtime occupancy
// comes from grid size). Grid (64,4,2): blockIdx.z = 2048-key half.
// 512 blocks -> 2 blocks/CU resident -> one wave's MFMA hides the other's
// L2/barrier stalls. Blocks write UNNORMALIZED fp32 partial O + partial l;
// attn_combine sums the halves (plain addition — no online max needed).
__global__ __launch_bounds__(256) void attn_kernel(
    const u16* __restrict__ q, const u16* __restrict__ k,
    const u16* __restrict__ vt, float* __restrict__ Op, float* __restrict__ Lb)
{
  __shared__ u16 P[2][64][72];   // [buf][q][key] bf16, 18.4 KB
  __shared__ float Lp[4][64];
  const int b   = blockIdx.y;
  const int kz  = blockIdx.z;
  const int tid = threadIdx.x;
  const int w   = tid >> 6, lane = tid & 63;
  const int lm  = lane & 15, q4 = lane >> 4;
  const int m0  = blockIdx.x * 64;
  const int base = kz * 2048;
  const u16* qb = q  + (size_t)b * 4096 * 256;
  const u16* kb = k  + (size_t)b * 4096 * 256;
  const u16* vb = vt + (size_t)b * 256 * 4096;

  // Q fragments for 4 q-tiles (held all kernel)
  v8s qf[4][8];
#pragma unroll
  for (int qt = 0; qt < 4; qt++) {
    const u16* qrow = qb + (size_t)(m0 + qt * 16 + lm) * 256 + q4 * 8;
#pragma unroll
    for (int kf = 0; kf < 8; kf++) qf[qt][kf] = *(const v8s*)(qrow + kf * 32);
  }

  v4f o[4][4];
#pragma unroll
  for (int qt = 0; qt < 4; qt++)
#pragma unroll
    for (int ct = 0; ct < 4; ct++) o[qt][ct] = (v4f){0.f, 0.f, 0.f, 0.f};
  float lsum[4][4];
#pragma unroll
  for (int qt = 0; qt < 4; qt++)
#pragma unroll
    for (int r = 0; r < 4; r++) lsum[qt][r] = 0.f;

  // K fragments for first chunk of this half
  v8s kfr[8], kfr2[8];
  {
    const u16* krow = kb + (size_t)(base + w * 16 + lm) * 256 + q4 * 8;
#pragma unroll
    for (int kf = 0; kf < 8; kf++) kfr[kf] = *(const v8s*)(krow + kf * 32);
  }

  for (int s0 = base; s0 < base + 2048; s0 += 64) {
    const int pb = (s0 >> 6) & 1;
    // V loads for this chunk, issued early
    v8s vfr[4][2];
#pragma unroll
    for (int ct = 0; ct < 4; ct++) {
      const u16* vrow = vb + (size_t)(w * 64 + ct * 16 + lm) * 4096 + s0 + q4 * 8;
#pragma unroll
      for (int ks = 0; ks < 2; ks++) vfr[ct][ks] = *(const v8s*)(vrow + ks * 32);
    }
    // phase A: S[64q x 16k] strips
    v4f sc[4];
#pragma unroll
    for (int qt = 0; qt < 4; qt++) sc[qt] = (v4f){0.f, 0.f, 0.f, 0.f};
#pragma unroll
    for (int kf = 0; kf < 8; kf++)
#pragma unroll
      for (int qt = 0; qt < 4; qt++)
        sc[qt] = __builtin_amdgcn_mfma_f32_16x16x32_bf16(qf[qt][kf], kfr[kf], sc[qt], 0, 0, 0);
    // K prefetch for next chunk (wraps within the half; last-iter wrap harmless)
    {
      const int sn = base + (((s0 - base) + 64) & 2047);
      const u16* krn = kb + (size_t)(sn + w * 16 + lm) * 256 + q4 * 8;
#pragma unroll
      for (int kf = 0; kf < 8; kf++) kfr2[kf] = *(const v8s*)(krn + kf * 32);
    }
    // exp -> P
#pragma unroll
    for (int qt = 0; qt < 4; qt++)
#pragma unroll
      for (int r = 0; r < 4; r++) {
        const float e = __expf(sc[qt][r] * 0.0625f);
        lsum[qt][r] += e;
        P[pb][qt * 16 + q4 * 4 + r][w * 16 + lm] = f2b(e);
      }
    __syncthreads();
    // phase B: O[64q x 64ch(w)] += P * V
#pragma unroll
    for (int qt = 0; qt < 4; qt++) {
      const v8s pf0 = *(const v8s*)(&P[pb][qt * 16 + lm][q4 * 8]);
      const v8s pf1 = *(const v8s*)(&P[pb][qt * 16 + lm][32 + q4 * 8]);
#pragma unroll
      for (int ct = 0; ct < 4; ct++) {
        o[qt][ct] = __builtin_amdgcn_mfma_f32_16x16x32_bf16(pf0, vfr[ct][0], o[qt][ct], 0, 0, 0);
        o[qt][ct] = __builtin_amdgcn_mfma_f32_16x16x32_bf16(pf1, vfr[ct][1], o[qt][ct], 0, 0, 0);
      }
    }
#pragma unroll
    for (int kf = 0; kf < 8; kf++) kfr[kf] = kfr2[kf];
  }

  // partial l: butterfly over the 16 key-lanes, then sum the 4 waves
#pragma unroll
  for (int qt = 0; qt < 4; qt++)
#pragma unroll
    for (int r = 0; r < 4; r++) {
      float t = lsum[qt][r];
      t += __shfl_xor(t, 1); t += __shfl_xor(t, 2);
      t += __shfl_xor(t, 4); t += __shfl_xor(t, 8);
      lsum[qt][r] = t;
    }
  if (lm == 0) {
#pragma unroll
    for (int qt = 0; qt < 4; qt++)
#pragma unroll
      for (int r = 0; r < 4; r++) Lp[w][qt * 16 + q4 * 4 + r] = lsum[qt][r];
  }
  __syncthreads();
  const size_t row16k = (size_t)b * 4096 + m0;        // global row of this tile
  if (tid < 64)
    Lb[(size_t)kz * 16384 + row16k + tid] = Lp[0][tid] + Lp[1][tid] + Lp[2][tid] + Lp[3][tid];

  // unnormalized fp32 partial O
  float* opb = Op + ((size_t)kz * 16384 + row16k) * 256;
#pragma unroll
  for (int qt = 0; qt < 4; qt++)
#pragma unroll
    for (int r = 0; r < 4; r++) {
      const size_t rbase = (size_t)(qt * 16 + q4 * 4 + r) * 256 + w * 64;
#pragma unroll
      for (int ct = 0; ct < 4; ct++)
        opb[rbase + ct * 16 + lm] = o[qt][ct][r];
    }
}

// ---------------- combine the two key-half partials ----------------
// grid 4096, block 256: 4 rows/block, one row per wave, float4 per lane.
__global__ void attn_combine(const float* __restrict__ Op, const float* __restrict__ Lb,
                             u16* __restrict__ ao)
{
  const int wid = threadIdx.x >> 6, lane = threadIdx.x & 63;
  const size_t row = (size_t)blockIdx.x * 4 + wid;
  const float linv = 1.0f / (Lb[row] + Lb[16384 + row]);
  const float4 o0 = *(const float4*)(Op + row * 256 + lane * 4);
  const float4 o1 = *(const float4*)(Op + (16384 + row) * 256 + lane * 4);
  ushort4 rb;
  rb.x = f2b((o0.x + o1.x) * linv);
  rb.y = f2b((o0.y + o1.y) * linv);
  rb.z = f2b((o0.z + o1.z) * linv);
  rb.w = f2b((o0.w + o1.w) * linv);
  *(ushort4*)(ao + row * 256 + lane * 4) = rb;
}

// ---------------- proj GEMM + bias + residual ----------------
__global__ __launch_bounds__(256) void gemm_proj(
    const u16* __restrict__ A, const u16* __restrict__ Wt, const float* __restrict__ bias,
    const float* __restrict__ xn_f, float* __restrict__ out)
{
  const int wid = threadIdx.x >> 6, lane = threadIdx.x & 63;
  const int lm = lane & 15, q4 = lane >> 4;
  const int m0 = blockIdx.x * 64 + wid * 16;
  const u16* arow = A + (size_t)(m0 + lm) * 256 + q4 * 8;
  v8s af[8];
#pragma unroll
  for (int kf = 0; kf < 8; kf++) af[kf] = *(const v8s*)(arow + kf * 32);
#pragma unroll
  for (int ct = 0; ct < 16; ct++) {
    const int c = ct * 16 + lm;
    const u16* wrow = Wt + (size_t)c * 256 + q4 * 8;
    v4f acc = {0.f, 0.f, 0.f, 0.f};
#pragma unroll
    for (int kf = 0; kf < 8; kf++)
      acc = __builtin_amdgcn_mfma_f32_16x16x32_bf16(af[kf], *(const v8s*)(wrow + kf * 32), acc, 0, 0, 0);
    const float bb = bias[c];
#pragma unroll
    for (int r = 0; r < 4; r++) {
      const size_t idx = (size_t)(m0 + q4 * 4 + r) * 256 + c;
      out[idx] = xn_f[idx] + acc[r] + bb;
    }
  }
}

extern "C" void kernel_launch(void* const* d_in, const int* in_sizes, int n_in,
                              void* d_out, int out_size, void* d_ws, size_t ws_size,
                              hipStream_t stream)
{
  (void)in_sizes; (void)n_in; (void)out_size; (void)ws_size;
  const float* inputs  = (const float*)d_in[0];
  const float* context = (const float*)d_in[1];
  const float* Wq = (const float*)d_in[2];
  const float* bq = (const float*)d_in[3];
  const float* Wk = (const float*)d_in[4];
  const float* bk = (const float*)d_in[5];
  const float* Wv = (const float*)d_in[6];
  const float* bv = (const float*)d_in[7];
  const float* Wp = (const float*)d_in[8];
  const float* bp = (const float*)d_in[9];
  const float* gamma = (const float*)d_in[10];
  const float* beta  = (const float*)d_in[11];
  float* out = (float*)d_out;

  char* p = (char*)d_ws;
  float* xn_f = (float*)p; p += (size_t)16384 * 256 * 4;
  u16* xn_b   = (u16*)p;   p += (size_t)16384 * 256 * 2;
  u16* ctx_b  = (u16*)p;   p += (size_t)16384 * 256 * 2;
  u16* qbuf   = (u16*)p;   p += (size_t)16384 * 256 * 2;
  u16* kbuf   = (u16*)p;   p += (size_t)16384 * 256 * 2;
  u16* vtbuf  = (u16*)p;   p += (size_t)16384 * 256 * 2;
  u16* wqt = (u16*)p; p += (size_t)256 * 256 * 2;
  u16* wkt = (u16*)p; p += (size_t)256 * 256 * 2;
  u16* wvt = (u16*)p; p += (size_t)256 * 256 * 2;
  u16* wpt = (u16*)p; p += (size_t)256 * 256 * 2;
  float* Opart = (float*)p; p += (size_t)2 * 16384 * 256 * 4;   // 32 MB
  float* Lpart = (float*)p; p += (size_t)2 * 16384 * 4;         // 128 KB
  u16* aobuf = xn_b;  // xn_b dead after gemm_qkv

  ln_prep<<<dim3(4096, 2), 256, 0, stream>>>(inputs, context, gamma, beta, xn_f, xn_b, ctx_b);
  wtrans<<<dim3(16, 4), 256, 0, stream>>>(Wq, Wk, Wv, Wp, wqt, wkt, wvt, wpt);
  gemm_qkv<<<dim3(256, 3), 256, 0, stream>>>(xn_b, ctx_b, wqt, wkt, wvt, bq, bk, bv, qbuf, kbuf, vtbuf);
  attn_kernel<<<dim3(64, 4, 2), 256, 0, stream>>>(qbuf, kbuf, vtbuf, Opart, Lpart);
  attn_combine<<<dim3(4096), 256, 0, stream>>>(Opart, Lpart, aobuf);
  gemm_proj<<<dim3(256), 256, 0, stream>>>(aobuf, wpt, bp, xn_f, out);
}